// Round 4
// baseline (101.417 us; speedup 1.0000x reference)
//
#include <hip/hip_runtime.h>
#include <math.h>

// PVConv2d: out = exp0(relu(conv3x3(log0(x), W) + bias)), Poincare ball c=0.01.
// x: [4,32,256,256] f32, Wk: [9,32,32] f32 ([k][o][c]), bias: [32] f32.
// R3: occupancy attack. Wave owns 32 px (2 M-tiles) -> 8192 waves = 8 waves/SIMD
// (vs 4 before; wave->64px capped the whole chip at 16 waves/CU).
//   - 512-thr blocks, tile 32x8, grid 1024 = 4 blocks/CU, all resident.
//   - LDS = u only (340 rows x 64B swizzled, 21.76 KB); v phase aliases as bf16.
//   - W pre-converted to bf16 in d_ws by a tiny pre-kernel; B-frags from L2.
//   - Staging: aligned float4 global loads, task=(row, f4-slot, ch-quarter),
//     per-pixel norm via shfl_xor over the 4 channel-quarter lanes.
//   - __launch_bounds__(512,8) caps VGPR at 64 for the 8/SIMD target.

#define TW 32
#define TH 8
#define HW_ 34
#define NPIX 340
#define CIN 32
#define COUT 32

typedef __attribute__((ext_vector_type(8))) short bf16x8;
typedef __attribute__((ext_vector_type(4))) float f32x4;

__device__ inline unsigned short f2bf(float f) {
    unsigned int u = __builtin_bit_cast(unsigned int, f);
    return (unsigned short)((u + 0x7FFFu + ((u >> 16) & 1u)) >> 16);   // RNE
}
__device__ inline unsigned int pk2(float a, float b) {
    return (unsigned int)f2bf(a) | ((unsigned int)f2bf(b) << 16);
}

__global__ __launch_bounds__(256) void wprep_kernel(
    const float* __restrict__ Wk, unsigned short* __restrict__ wsW)
{
    int i = blockIdx.x * 256 + threadIdx.x;
    if (i < 9 * 32 * 32) wsW[i] = f2bf(Wk[i]);
}

__global__ __launch_bounds__(512, 8) void pvconv_kernel(
    const float* __restrict__ x, const unsigned short* __restrict__ wsW,
    const float* __restrict__ bias, float* __restrict__ out)
{
    __shared__ __align__(16) unsigned char smem[NPIX * 64];   // 21760 B; v aliases (20480 B)
    unsigned char* u8 = smem;

    const int t  = threadIdx.x;
    const int x0 = blockIdx.x * TW, y0 = blockIdx.y * TH, b = blockIdx.z;

    // ---- stage halo: aligned float4 loads, log0, bf16 frags -> LDS ----
    // task = (hy 0..9, j 0..9 float4-slot, cq 0..3 channel-quarter): 400 tasks
    if (t < 400) {
        const int hy = t / 40, rem = t - hy * 40, j = rem >> 2, cq = rem & 3;
        const int gy = y0 - 1 + hy;
        const int gxb = x0 - 4 + 4 * j;              // covers px = 4j-3 .. 4j
        const bool ok = ((unsigned)gy < 256u) && !(j == 0 && x0 == 0)
                                              && !(j == 9 && x0 == 224);
        float vv[4][8];
        if (ok) {
            const float* xp = x + (size_t)(b * CIN + cq * 8) * 65536 + gy * 256 + gxb;
            #pragma unroll
            for (int cc = 0; cc < 8; ++cc) {
                float4 f4 = *(const float4*)(xp + (size_t)cc * 65536);
                vv[0][cc] = f4.x; vv[1][cc] = f4.y; vv[2][cc] = f4.z; vv[3][cc] = f4.w;
            }
        } else {
            #pragma unroll
            for (int i = 0; i < 4; ++i)
                #pragma unroll
                for (int cc = 0; cc < 8; ++cc) vv[i][cc] = 0.f;
        }
        float s4[4];
        #pragma unroll
        for (int i = 0; i < 4; ++i) {
            float ss = 0.f;
            #pragma unroll
            for (int cc = 0; cc < 8; ++cc) ss = fmaf(vv[i][cc], vv[i][cc], ss);
            ss += __shfl_xor(ss, 1);                 // partners share (hy,j), differ cq
            ss += __shfl_xor(ss, 2);
            float n = fmaxf(sqrtf(ss), 1e-7f);
            float z = fminf(0.1f * n, 1.f - 1e-6f);
            float at = 0.5f * __logf((1.f + z) / (1.f - z));   // artanh(z)
            s4[i] = at / (0.1f * n);
        }
        const int i0 = (j == 0) ? 3 : 0, i1 = (j == 9) ? 0 : 3;
        #pragma unroll
        for (int i = 0; i < 4; ++i) {
            if (i < i0 || i > i1) continue;
            int p = hy * 34 + 4 * j - 3 + i;         // halo pixel index
            unsigned int pkk[4];
            #pragma unroll
            for (int w = 0; w < 4; ++w)
                pkk[w] = pk2(vv[i][2 * w] * s4[i], vv[i][2 * w + 1] * s4[i]);
            *(uint4*)(u8 + p * 64 + ((cq ^ ((p >> 1) & 3)) << 4)) = *(uint4*)pkk;
        }
    }
    __syncthreads();

    // ---- MFMA conv: wave -> 32 px (out row wv), 2 M-tiles x 2 N-tiles ----
    const int wv = t >> 6, lane = t & 63, m = lane & 15, quad = lane >> 4;
    const float bia0 = bias[m], bia1 = bias[16 + m];

    f32x4 acc[2][2];
    #pragma unroll
    for (int n = 0; n < 2; ++n)
        #pragma unroll
        for (int mt = 0; mt < 2; ++mt) acc[n][mt] = (f32x4)0.f;

    const int pb0 = wv * 34 + m;         // halo pixel for tap(0,0), mt=0
    #pragma unroll
    for (int tap = 0; tap < 9; ++tap) {
        const int dy = tap / 3, dx = tap - dy * 3;
        const unsigned short* wrow = wsW + (tap * 32 + m) * 32 + quad * 8;
        bf16x8 B0 = *(const bf16x8*)wrow;
        bf16x8 B1 = *(const bf16x8*)(wrow + 512);    // o + 16
        #pragma unroll
        for (int mt = 0; mt < 2; ++mt) {
            int p = pb0 + mt * 16 + dy * 34 + dx;
            bf16x8 A = *(const bf16x8*)(u8 + p * 64 + ((quad ^ ((p >> 1) & 3)) << 4));
            acc[0][mt] = __builtin_amdgcn_mfma_f32_16x16x32_bf16(A, B0, acc[0][mt], 0, 0, 0);
            acc[1][mt] = __builtin_amdgcn_mfma_f32_16x16x32_bf16(A, B1, acc[1][mt], 0, 0, 0);
        }
    }
    __syncthreads();   // all waves done reading u before v overwrites

    // ---- bias+relu, v (bf16, stride 40) -> LDS ----
    // D layout: col = lane&15 -> channel, row = quad*4+r -> pixel offset
    unsigned short* vb = (unsigned short*)smem;
    #pragma unroll
    for (int n = 0; n < 2; ++n)
        #pragma unroll
        for (int mt = 0; mt < 2; ++mt)
            #pragma unroll
            for (int r = 0; r < 4; ++r) {
                int P = wv * 32 + mt * 16 + quad * 4 + r;
                float val = acc[n][mt][r] + (n ? bia1 : bia0);
                vb[P * 40 + n * 16 + m] = f2bf(fmaxf(val, 0.f));
            }
    __syncthreads();

    // ---- exp0 + store: thread -> (pixel t>>1, channel-half t&1) ----
    {
        const int pix = t >> 1, h = t & 1;
        const unsigned short* vp = (const unsigned short*)smem + pix * 40 + h * 16;
        uint4 q0 = *(const uint4*)vp;
        uint4 q1 = *(const uint4*)(vp + 8);
        unsigned int wds[8] = {q0.x, q0.y, q0.z, q0.w, q1.x, q1.y, q1.z, q1.w};
        float qf[16];
        #pragma unroll
        for (int k = 0; k < 8; ++k) {
            qf[2 * k]     = __builtin_bit_cast(float, wds[k] << 16);
            qf[2 * k + 1] = __builtin_bit_cast(float, wds[k] & 0xFFFF0000u);
        }
        float ss = 0.f;
        #pragma unroll
        for (int k = 0; k < 16; ++k) ss = fmaf(qf[k], qf[k], ss);
        ss += __shfl_xor(ss, 1);                     // partner holds other 16 channels
        float n = fmaxf(sqrtf(ss), 1e-7f);
        float a = 0.1f * n;
        float e = __expf(-2.f * a);
        float s = (1.f - e) / ((1.f + e) * a);       // tanh(a)/a
        const int py = pix >> 5, px = pix & 31;
        const size_t base = (size_t)b * COUT * 65536 + (size_t)(y0 + py) * 256 + (x0 + px);
        #pragma unroll
        for (int cc = 0; cc < 16; ++cc)
            out[base + (size_t)(h * 16 + cc) * 65536] = s * qf[cc];
    }
}

extern "C" void kernel_launch(void* const* d_in, const int* in_sizes, int n_in,
                              void* d_out, int out_size, void* d_ws, size_t ws_size,
                              hipStream_t stream) {
    const float* x    = (const float*)d_in[0];
    const float* Wk   = (const float*)d_in[1];
    const float* bias = (const float*)d_in[2];
    float* out = (float*)d_out;
    unsigned short* wsW = (unsigned short*)d_ws;     // 9*32*32 bf16 = 18.4 KB

    wprep_kernel<<<dim3(36), dim3(256), 0, stream>>>(Wk, wsW);
    dim3 grid(256 / TW, 256 / TH, 4);                // 8 x 32 x 4 = 1024 blocks
    pvconv_kernel<<<grid, dim3(512), 0, stream>>>(x, wsW, bias, out);
}